// Round 6
// baseline (121.986 us; speedup 1.0000x reference)
//
#include <hip/hip_runtime.h>
#include <hip/hip_bf16.h>

#define N_ATOMS 262144
#define NGRAPH  2048
#define INV_SCALE 0.17677669529663687f  // 1/sqrt(32)

typedef float f32x2 __attribute__((ext_vector_type(2)));
typedef float f32x4 __attribute__((ext_vector_type(4)));
typedef short s16x8 __attribute__((ext_vector_type(8)));
typedef unsigned int u32;
typedef unsigned short ushort_t;

// packed fp32 fma with scalar broadcast from LOW/HIGH half of a (R5-verified)
__device__ __forceinline__ f32x2 pk_fma_blo(f32x2 a, f32x2 b, f32x2 c) {
  f32x2 d; asm("v_pk_fma_f32 %0, %1, %2, %3 op_sel_hi:[0,1,1]"
               : "=v"(d) : "v"(a), "v"(b), "v"(c)); return d;
}
__device__ __forceinline__ f32x2 pk_fma_bhi(f32x2 a, f32x2 b, f32x2 c) {
  f32x2 d; asm("v_pk_fma_f32 %0, %1, %2, %3 op_sel:[1,0,0]"
               : "=v"(d) : "v"(a), "v"(b), "v"(c)); return d;
}
__device__ __forceinline__ u32 cvt2_bf16(float lo, float hi) {
  u32 d; asm("v_cvt_pk_bf16_f32 %0, %1, %2" : "=v"(d) : "v"(lo), "v"(hi)); return d;
}

// ---------------- K1: P[h][i] = sum_d Wk[i][h*32+d]*q[h][d]; also bf16 copy.
__global__ void k_prep(const float* __restrict__ Wk, const float* __restrict__ bk,
                       const float* __restrict__ q, float* __restrict__ P,
                       ushort_t* __restrict__ Pbf, float* __restrict__ c) {
  int h = blockIdx.x, i = threadIdx.x;
  float s = 0.f;
  #pragma unroll
  for (int d = 0; d < 32; ++d)
    s = fmaf(Wk[i * 256 + h * 32 + d], q[h * 32 + d], s);
  P[h * 256 + i] = s;
  __hip_bfloat16 hb = __float2bfloat16(s);
  Pbf[h * 256 + i] = *reinterpret_cast<ushort_t*>(&hb);
  if (i == 0) {
    float cc = 0.f;
    #pragma unroll
    for (int d = 0; d < 32; ++d) cc = fmaf(bk[h * 32 + d], q[h * 32 + d], cc);
    c[h] = cc;
  }
}

// ---------------- K1b: segment bounds via one binary search per graph.
__global__ void k_bounds(const int* __restrict__ batch, int* __restrict__ bounds) {
  int g = blockIdx.x * blockDim.x + threadIdx.x;
  if (g >= NGRAPH) return;
  int lo = 0, hi = N_ATOMS;
  while (lo < hi) {
    int mid = (lo + hi) >> 1;
    if (batch[mid] < g) lo = mid + 1; else hi = mid;
  }
  bounds[2 * g] = lo;
  if (g > 0) bounds[2 * g - 1] = lo;
  if (g == NGRAPH - 1) bounds[2 * g + 1] = N_ATOMS;
}

// ---------------- K2: fused scores (bf16 MFMA) + exp + fp32 accumulate.
// One block per graph, 4 waves, each wave owns 16-atom chunks (stride 64).
// Per chunk: stage x->bf16 LDS (XOR swizzle) -> 8x mfma 16x16x32 vs hoisted
// P-frags -> exp (fp32, masked) -> e-table -> fp32 pk accumulate with x
// re-loaded from global (L2-hot). Scores-only bf16; A-path exact fp32.
__global__ __launch_bounds__(256) void k_fused(const float* __restrict__ x,
                                               const ushort_t* __restrict__ Pbf,
                                               const float* __restrict__ c,
                                               const int* __restrict__ bounds,
                                               float* __restrict__ Ag) {
  int b = blockIdx.x;
  int seg_s = bounds[2 * b], seg_e = bounds[2 * b + 1];
  int t = threadIdx.x, lane = t & 63, wv = t >> 6;
  int hq = lane & 15;   // MFMA col (head; cols 8-15 duplicate 0-7)
  int qq = lane >> 4;   // MFMA quarter

  __shared__ union ShU {
    ushort_t xbf[4][16][256];  // per-wave bf16 stage, 32 KB
    float As[4][8][256];       // epilogue partials, 32 KB (time-disjoint)
  } sh;
  __shared__ float etab[4][16][8];  // per-wave e-table, 2 KB
  __shared__ float dws[4][8];
  __shared__ float dinvs[8];

  // Hoist B-frags: B[k = kt*32 + qq*8 + j][col] = Pbf[col&7][kt*32 + qq*8 + j]
  s16x8 bfrag[8];
  #pragma unroll
  for (int kt = 0; kt < 8; ++kt)
    bfrag[kt] = *reinterpret_cast<const s16x8*>(Pbf + (hq & 7) * 256 + kt * 32 + qq * 8);
  float cl = c[hq & 7];

  f32x2 A2[8][2];
  #pragma unroll
  for (int k = 0; k < 8; ++k) { A2[k][0] = (f32x2)0.f; A2[k][1] = (f32x2)0.f; }
  float dacc = 0.f;

  char* xb = (char*)&sh.xbf[wv][0][0];

  for (int cb = seg_s + 16 * wv; cb < seg_e; cb += 64) {
    // ---- phase S: stage 16 rows as bf16, XOR-swizzled (16B granules)
    #pragma unroll
    for (int a = 0; a < 16; ++a) {
      int n = cb + a; n = n < seg_e ? n : seg_e - 1;
      f32x4 xv = *reinterpret_cast<const f32x4*>(x + (size_t)n * 256 + 4 * lane);
      u32 d0 = cvt2_bf16(xv[0], xv[1]);
      u32 d1 = cvt2_bf16(xv[2], xv[3]);
      *reinterpret_cast<uint2*>(xb + a * 512 + ((8 * lane) ^ ((a & 7) << 4))) =
          make_uint2(d0, d1);
    }
    // ---- phase M: scores[atom, head] via 8 chained MFMAs over K=256
    f32x4 acc = {0.f, 0.f, 0.f, 0.f};
    #pragma unroll
    for (int kt = 0; kt < 8; ++kt) {
      s16x8 af = *reinterpret_cast<const s16x8*>(
          xb + hq * 512 + ((kt * 64 + qq * 16) ^ ((hq & 7) << 4)));
      acc = __builtin_amdgcn_mfma_f32_16x16x32_bf16(af, bfrag[kt], acc, 0, 0, 0);
    }
    // ---- exp + mask + e-table + denominator partials
    float ptile = 0.f;
    float ev[4];
    #pragma unroll
    for (int j = 0; j < 4; ++j) {
      int aj = cb + qq * 4 + j;  // C row = atom-in-chunk (m89-verified layout)
      float sc = (acc[j] + cl) * INV_SCALE;
      float ee = __expf(sc);
      ee = (aj < seg_e) ? ee : 0.f;
      ev[j] = ee;
      ptile += ee;
    }
    ptile += __shfl_xor(ptile, 16, 64);
    ptile += __shfl_xor(ptile, 32, 64);
    dacc += ptile;
    if (hq < 8) {
      #pragma unroll
      for (int j = 0; j < 4; ++j) etab[wv][qq * 4 + j][hq] = ev[j];
    }
    // ---- phase A: fp32 accumulate, x re-loaded (L2-hot), 2-atom ILP
    #pragma unroll
    for (int a = 0; a < 16; a += 2) {
      int n0 = cb + a;     n0 = n0 < seg_e ? n0 : seg_e - 1;
      int n1 = cb + a + 1; n1 = n1 < seg_e ? n1 : seg_e - 1;
      f32x4 x0 = *reinterpret_cast<const f32x4*>(x + (size_t)n0 * 256 + 4 * lane);
      f32x4 x1 = *reinterpret_cast<const f32x4*>(x + (size_t)n1 * 256 + 4 * lane);
      f32x4 eA0 = *reinterpret_cast<const f32x4*>(&etab[wv][a][0]);
      f32x4 eA1 = *reinterpret_cast<const f32x4*>(&etab[wv][a][4]);
      f32x4 eB0 = *reinterpret_cast<const f32x4*>(&etab[wv][a + 1][0]);
      f32x4 eB1 = *reinterpret_cast<const f32x4*>(&etab[wv][a + 1][4]);
      f32x2 x0lo = __builtin_shufflevector(x0, x0, 0, 1);
      f32x2 x0hi = __builtin_shufflevector(x0, x0, 2, 3);
      f32x2 x1lo = __builtin_shufflevector(x1, x1, 0, 1);
      f32x2 x1hi = __builtin_shufflevector(x1, x1, 2, 3);
      f32x2 ea[4] = { __builtin_shufflevector(eA0, eA0, 0, 1),
                      __builtin_shufflevector(eA0, eA0, 2, 3),
                      __builtin_shufflevector(eA1, eA1, 0, 1),
                      __builtin_shufflevector(eA1, eA1, 2, 3) };
      f32x2 eb[4] = { __builtin_shufflevector(eB0, eB0, 0, 1),
                      __builtin_shufflevector(eB0, eB0, 2, 3),
                      __builtin_shufflevector(eB1, eB1, 0, 1),
                      __builtin_shufflevector(eB1, eB1, 2, 3) };
      #pragma unroll
      for (int j = 0; j < 4; ++j) {
        A2[2*j][0]   = pk_fma_blo(ea[j], x0lo, A2[2*j][0]);
        A2[2*j][1]   = pk_fma_blo(ea[j], x0hi, A2[2*j][1]);
        A2[2*j+1][0] = pk_fma_bhi(ea[j], x0lo, A2[2*j+1][0]);
        A2[2*j+1][1] = pk_fma_bhi(ea[j], x0hi, A2[2*j+1][1]);
        A2[2*j][0]   = pk_fma_blo(eb[j], x1lo, A2[2*j][0]);
        A2[2*j][1]   = pk_fma_blo(eb[j], x1hi, A2[2*j][1]);
        A2[2*j+1][0] = pk_fma_bhi(eb[j], x1lo, A2[2*j+1][0]);
        A2[2*j+1][1] = pk_fma_bhi(eb[j], x1hi, A2[2*j+1][1]);
      }
    }
  }

  // ---- epilogue: union hazard barrier, then cross-wave reduce + normalize
  __syncthreads();
  #pragma unroll
  for (int k = 0; k < 8; ++k) {
    float4 av;
    av.x = A2[k][0][0]; av.y = A2[k][0][1];
    av.z = A2[k][1][0]; av.w = A2[k][1][1];
    *reinterpret_cast<float4*>(&sh.As[wv][k][4 * lane]) = av;
  }
  if (lane < 8) dws[wv][lane] = dacc;
  __syncthreads();
  if (t < 8) {
    float ds = dws[0][t] + dws[1][t] + dws[2][t] + dws[3][t];
    dinvs[t] = ds > 0.f ? 1.0f / ds : 0.f;
  }
  __syncthreads();
  #pragma unroll
  for (int r2 = 0; r2 < 8; ++r2) {
    float v = sh.As[0][r2][t] + sh.As[1][r2][t] + sh.As[2][r2][t] + sh.As[3][r2][t];
    Ag[(size_t)b * 2048 + r2 * 256 + t] = v * dinvs[r2];
  }
}

// ---------------- K5: att = A . Wv + bv (nonempty), out = att . Wo + bo
__global__ __launch_bounds__(256) void k_out(const float* __restrict__ Ag,
                                             const int* __restrict__ bounds,
                                             const float* __restrict__ Wv,
                                             const float* __restrict__ bv,
                                             const float* __restrict__ Wo,
                                             const float* __restrict__ bo,
                                             float* __restrict__ out) {
  __shared__ float Alds[4 * 2048];   // 32 KB
  __shared__ float attlds[4 * 256];  // 4 KB
  __shared__ float eflag[4];
  int b0 = blockIdx.x * 4;
  int t = threadIdx.x;
  #pragma unroll
  for (int r = 0; r < 32; ++r) {
    int idx = r * 256 + t;
    Alds[idx] = Ag[(size_t)b0 * 2048 + idx];
  }
  if (t < 4) {
    int s = bounds[2 * (b0 + t)], e = bounds[2 * (b0 + t) + 1];
    eflag[t] = (e > s) ? 1.0f : 0.0f;
  }
  __syncthreads();
  int h = t >> 5;
  float bvk = bv[t];
  float acc[4];
  #pragma unroll
  for (int g = 0; g < 4; ++g) acc[g] = 0.f;
  for (int i4 = 0; i4 < 64; ++i4) {
    float aa[4][4];
    #pragma unroll
    for (int g = 0; g < 4; ++g) {
      float4 v = *reinterpret_cast<const float4*>(&Alds[g * 2048 + h * 256 + i4 * 4]);
      aa[g][0] = v.x; aa[g][1] = v.y; aa[g][2] = v.z; aa[g][3] = v.w;
    }
    #pragma unroll
    for (int j = 0; j < 4; ++j) {
      float wvv = Wv[(size_t)(i4 * 4 + j) * 256 + t];
      #pragma unroll
      for (int g = 0; g < 4; ++g) acc[g] = fmaf(aa[g][j], wvv, acc[g]);
    }
  }
  #pragma unroll
  for (int g = 0; g < 4; ++g) attlds[g * 256 + t] = acc[g] + bvk * eflag[g];
  __syncthreads();
  float boj = bo[t];
  float o[4];
  #pragma unroll
  for (int g = 0; g < 4; ++g) o[g] = boj;
  for (int k4 = 0; k4 < 64; ++k4) {
    float aa[4][4];
    #pragma unroll
    for (int g = 0; g < 4; ++g) {
      float4 v = *reinterpret_cast<const float4*>(&attlds[g * 256 + k4 * 4]);
      aa[g][0] = v.x; aa[g][1] = v.y; aa[g][2] = v.z; aa[g][3] = v.w;
    }
    #pragma unroll
    for (int j = 0; j < 4; ++j) {
      float wo = Wo[(size_t)(k4 * 4 + j) * 256 + t];
      #pragma unroll
      for (int g = 0; g < 4; ++g) o[g] = fmaf(aa[g][j], wo, o[g]);
    }
  }
  #pragma unroll
  for (int g = 0; g < 4; ++g) out[(size_t)(b0 + g) * 256 + t] = o[g];
}

extern "C" void kernel_launch(void* const* d_in, const int* in_sizes, int n_in,
                              void* d_out, int out_size, void* d_ws, size_t ws_size,
                              hipStream_t stream) {
  const float* x   = (const float*)d_in[0];
  const int*   bat = (const int*)d_in[1];
  const float* q   = (const float*)d_in[2];
  const float* Wk  = (const float*)d_in[3];
  const float* bk  = (const float*)d_in[4];
  const float* Wv  = (const float*)d_in[5];
  const float* bv  = (const float*)d_in[6];
  const float* Wo  = (const float*)d_in[7];
  const float* bo  = (const float*)d_in[8];
  float* out = (float*)d_out;

  float* ws = (float*)d_ws;
  float*    P      = ws;                      // [0, 2048)
  float*    c      = ws + 2048;               // [2048, 2056)
  int*      bounds = (int*)(ws + 4096);       // [4096, 8192) as ints
  ushort_t* Pbf    = (ushort_t*)(ws + 8192);  // 2048 ushorts = [8192, 9216)
  float*    Ag     = ws + 16384;              // 2048*2048 floats

  k_prep<<<8, 256, 0, stream>>>(Wk, bk, q, P, Pbf, c);
  k_bounds<<<8, 256, 0, stream>>>(bat, bounds);
  k_fused<<<NGRAPH, 256, 0, stream>>>(x, Pbf, c, bounds, Ag);
  k_out<<<NGRAPH / 4, 256, 0, stream>>>(Ag, bounds, Wv, bv, Wo, bo, out);
}